// Round 14
// baseline (230.864 us; speedup 1.0000x reference)
//
#include <hip/hip_runtime.h>
#include <hip/hip_bf16.h>

#define DEV __device__ __forceinline__

typedef __bf16 bf16x8 __attribute__((ext_vector_type(8)));
typedef float  f32x4  __attribute__((ext_vector_type(4)));

// caps = {512,1024,2048,4096,1024,512,2048,1024}
// 128-row-tile cumsum: {0,4,12,28,60,68,72,88,96}
// 256-row-tile cumsum: {0,2,6,14,30,34,36,44,48}

DEV unsigned short f2bf(float f) {
  union { float f; unsigned u; } v; v.f = f;
  unsigned u = v.u;
  return (unsigned short)((u + 0x7FFFu + ((u >> 16) & 1u)) >> 16);  // RNE
}

DEV float bf2f(unsigned short s) {
  union { unsigned u; float f; } v; v.u = (unsigned)s << 16; return v.f;
}

DEV void gld_lds16(const void* g, void* l) {
  __builtin_amdgcn_global_load_lds(
      (const __attribute__((address_space(1))) unsigned int*)g,
      (__attribute__((address_space(3))) unsigned int*)l, 16, 0, 0);
}

#define WAITVM(N) asm volatile("s_waitcnt vmcnt(" #N ")" ::: "memory"); \
                  __builtin_amdgcn_sched_barrier(0)
#define WAITLG(N) asm volatile("s_waitcnt lgkmcnt(" #N ")" ::: "memory"); \
                  __builtin_amdgcn_sched_barrier(0)
#define BARRIER() __builtin_amdgcn_s_barrier(); __builtin_amdgcn_sched_barrier(0)

// ---------------------------------------------------------------------------
// Wc GEMM (round-9 best, 931 TF): 256x256 tile, 8 waves 2x4, wave-tile 128x64,
// BK=64, 128KB LDS, counted vmcnt + register fragment pipeline. UNCHANGED.
// ---------------------------------------------------------------------------
template <int KT_, int KLEN, int SK, int N_, int NCT, bool OUT_BF16,
          bool HAS_BIAS, int EDIV>
__global__ __launch_bounds__(512, 2)
void gemm256p(const unsigned short* __restrict__ A,
              const unsigned short* __restrict__ B,
              const float* __restrict__ bias,
              void* __restrict__ C0, void* __restrict__ C1) {
  __shared__ __align__(128) char lds[131072];
  constexpr int NT = KLEN / 64;

  const int tid  = threadIdx.x;
  const int lane = tid & 63;
  const int wv   = tid >> 6;
  const int wm   = wv >> 2;
  const int wn   = wv & 3;
  const int fr   = lane & 15;
  const int fq   = lane >> 4;

  int bid = blockIdx.x;
  const int nwg = gridDim.x;
  bid = (bid & 7) * (nwg >> 3) + (bid >> 3);

  int sk = 0;
  if constexpr (SK > 1) {
    const int per = nwg / SK;
    sk = bid / per;
    bid -= sk * per;
  }
  const int kStart = sk * KLEN;
  void* Cv = (SK > 1 && sk == 1) ? C1 : C0;

  const int rt = bid / NCT;
  const int ct = bid - rt * NCT;

  int e;
  if constexpr (EDIV > 0) {
    e = rt / EDIV;
  } else {
    const int cums[9] = {0, 2, 6, 14, 30, 34, 36, 44, 48};
    e = 0;
#pragma unroll
    for (int i = 1; i < 8; ++i) e += (rt >= cums[i]) ? 1 : 0;
  }

  const int grow0 = rt * 256;
  const int nloc0 = ct * 256;
  const unsigned short* Bg = B + (size_t)e * N_ * KT_;

  f32x4 acc[8][4];
#pragma unroll
  for (int i = 0; i < 8; ++i)
#pragma unroll
    for (int j = 0; j < 4; ++j) acc[i][j] = (f32x4){0.f, 0.f, 0.f, 0.f};

  auto stage_half = [&](int t, int h) {
    const int kb = kStart + t * 64;
    char* dst = lds + (h >> 1) * 65536 + (t & 1) * 32768 + (h & 1) * 16384;
    const unsigned short* src = (h < 2) ? A : Bg;
    const int row0 = (h < 2) ? (grow0 + (h & 1) * 128) : (nloc0 + (h & 1) * 128);
#pragma unroll
    for (int s = 0; s < 2; ++s) {
      int o  = s * 8192 + wv * 1024 + lane * 16;
      int r  = o >> 7;
      int cb = (o & 127) ^ ((r & 7) << 4);
      gld_lds16(src + (size_t)(row0 + r) * KT_ + kb + (cb >> 1),
                dst + s * 8192 + wv * 1024);
    }
  };

  stage_half(0, 0); stage_half(0, 1); stage_half(0, 2); stage_half(0, 3);
  if constexpr (NT > 1) { stage_half(1, 2); stage_half(1, 3); }

  const int brow0 = (wn & 1) * 64;

  for (int t = 0; t < NT; ++t) {
    char* Ah = lds + (t & 1) * 32768 + wm * 16384;
    char* Bh = lds + 65536 + (t & 1) * 32768 + ((wn >> 1) * 16384);

    if (t + 1 < NT) { WAITVM(4); } else { WAITVM(0); }
    BARRIER();                       // RAW: tile t visible to ALL waves

    bf16x8 bfr[4][2], afX[2][2], afY[2][2];
#pragma unroll
    for (int ni = 0; ni < 4; ++ni) {
      int r = brow0 + ni * 16 + fr;
#pragma unroll
      for (int k = 0; k < 2; ++k)
        bfr[ni][k] = *(bf16x8*)(Bh + r * 128 + ((k * 64 + fq * 16) ^ ((r & 7) << 4)));
    }
#pragma unroll
    for (int j = 0; j < 2; ++j) {
      int r = j * 16 + fr;
#pragma unroll
      for (int k = 0; k < 2; ++k)
        afX[j][k] = *(bf16x8*)(Ah + r * 128 + ((k * 64 + fq * 16) ^ ((r & 7) << 4)));
    }
#pragma unroll
    for (int j = 0; j < 2; ++j) {
      int r = 32 + j * 16 + fr;
#pragma unroll
      for (int k = 0; k < 2; ++k)
        afY[j][k] = *(bf16x8*)(Ah + r * 128 + ((k * 64 + fq * 16) ^ ((r & 7) << 4)));
    }
    if (t + 1 < NT) stage_half(t + 1, 0);
    WAITLG(4);                       // B + A0 done; A1 outstanding
    BARRIER();                       // WAR: b-slot gen t&1 writable
    __builtin_amdgcn_s_setprio(1);
#pragma unroll
    for (int k = 0; k < 2; ++k)
#pragma unroll
      for (int j = 0; j < 2; ++j)
#pragma unroll
        for (int ni = 0; ni < 4; ++ni)
          acc[j][ni] = __builtin_amdgcn_mfma_f32_16x16x32_bf16(
              afX[j][k], bfr[ni][k], acc[j][ni], 0, 0, 0);
    __builtin_amdgcn_s_setprio(0);
#pragma unroll
    for (int j = 0; j < 2; ++j) {
      int r = 64 + j * 16 + fr;
#pragma unroll
      for (int k = 0; k < 2; ++k)
        afX[j][k] = *(bf16x8*)(Ah + r * 128 + ((k * 64 + fq * 16) ^ ((r & 7) << 4)));
    }
    if (t + 1 < NT) stage_half(t + 1, 1);
    if (t + 2 < NT) stage_half(t + 2, 2);
    WAITLG(4);                       // A1 done; A2 outstanding
    __builtin_amdgcn_s_setprio(1);
#pragma unroll
    for (int k = 0; k < 2; ++k)
#pragma unroll
      for (int j = 0; j < 2; ++j)
#pragma unroll
        for (int ni = 0; ni < 4; ++ni)
          acc[2 + j][ni] = __builtin_amdgcn_mfma_f32_16x16x32_bf16(
              afY[j][k], bfr[ni][k], acc[2 + j][ni], 0, 0, 0);
    __builtin_amdgcn_s_setprio(0);
#pragma unroll
    for (int j = 0; j < 2; ++j) {
      int r = 96 + j * 16 + fr;
#pragma unroll
      for (int k = 0; k < 2; ++k)
        afY[j][k] = *(bf16x8*)(Ah + r * 128 + ((k * 64 + fq * 16) ^ ((r & 7) << 4)));
    }
    if (t + 2 < NT) stage_half(t + 2, 3);
    WAITLG(4);                       // A2 done; A3 outstanding
    __builtin_amdgcn_s_setprio(1);
#pragma unroll
    for (int k = 0; k < 2; ++k)
#pragma unroll
      for (int j = 0; j < 2; ++j)
#pragma unroll
        for (int ni = 0; ni < 4; ++ni)
          acc[4 + j][ni] = __builtin_amdgcn_mfma_f32_16x16x32_bf16(
              afX[j][k], bfr[ni][k], acc[4 + j][ni], 0, 0, 0);
    __builtin_amdgcn_s_setprio(0);
    WAITLG(0);                       // A3 done
    __builtin_amdgcn_s_setprio(1);
#pragma unroll
    for (int k = 0; k < 2; ++k)
#pragma unroll
      for (int j = 0; j < 2; ++j)
#pragma unroll
        for (int ni = 0; ni < 4; ++ni)
          acc[6 + j][ni] = __builtin_amdgcn_mfma_f32_16x16x32_bf16(
              afY[j][k], bfr[ni][k], acc[6 + j][ni], 0, 0, 0);
    __builtin_amdgcn_s_setprio(0);
  }

  // epilogue: D layout col=lane&15 (n), row=(lane>>4)*4+reg (m)  [m89]
#pragma unroll
  for (int ni = 0; ni < 4; ++ni) {
    int ncol = nloc0 + wn * 64 + ni * 16 + fr;
    float bv = 0.f;
    if constexpr (HAS_BIAS) bv = (bias + (size_t)e * N_)[ncol];
#pragma unroll
    for (int mi = 0; mi < 8; ++mi) {
      int m = grow0 + wm * 128 + mi * 16 + fq * 4;
#pragma unroll
      for (int j = 0; j < 4; ++j) {
        float val = acc[mi][ni][j] + bv;
        if constexpr (OUT_BF16)
          ((unsigned short*)Cv)[(size_t)(m + j) * N_ + ncol] = f2bf(val);
        else
          ((float*)Cv)[(size_t)(m + j) * N_ + ncol] = val;
      }
    }
  }
}

// ---------------------------------------------------------------------------
// Final GEMM, REG-STAGED (T14): out = x @ (p0+p1)^T + bc.
// Fuses the f32->bf16 conversion of x AND the split-K reduce of p0/p1 into
// the staging path (kills two standalone passes, ~20us). 128x128 tile,
// 4 waves 2x2, BK=64, 64KB LDS dbuf -> 2 blocks/CU, grid 768.
// One barrier per K-tile: writes target the opposite buffer; previous-tile
// reads were fenced by the prior barrier. Swizzle applied on BOTH ds_write
// and ds_read sides (rule 21). Global loads for t+1 issue before compute(t);
// vmcnt(0) drains them after the MFMA cluster (latency hidden).
// ---------------------------------------------------------------------------
__global__ __launch_bounds__(256, 2)
void gemm128rs(const float* __restrict__ X,
               const unsigned short* __restrict__ P0,
               const unsigned short* __restrict__ P1,
               const float* __restrict__ bias, float* __restrict__ C) {
  constexpr int K_ = 1024, N_ = 1024, NCT = 8, NT = K_ / 64;
  __shared__ __align__(128) char lds[2][32768];   // per buf: A 16KB + B 16KB

  const int tid  = threadIdx.x;
  const int lane = tid & 63;
  const int wv   = tid >> 6;     // 0..3
  const int wm   = wv >> 1;      // 0..1 (64 out-rows)
  const int wn   = wv & 1;       // 0..1 (64 out-cols)
  const int fr   = lane & 15;
  const int fq   = lane >> 4;

  int bid = blockIdx.x;
  const int nwg = gridDim.x;
  bid = (bid & 7) * (nwg >> 3) + (bid >> 3);   // XCD swizzle (nwg % 8 == 0)

  const int rt = bid / NCT;          // 0..95 (token 128-row tile)
  const int ct = bid - rt * NCT;     // 0..7  (output 128-col tile)

  const int cums[9] = {0, 4, 12, 28, 60, 68, 72, 88, 96};
  int e = 0;
#pragma unroll
  for (int i = 1; i < 8; ++i) e += (rt >= cums[i]) ? 1 : 0;

  const int grow0 = rt * 128;
  const int nloc0 = ct * 128;
  const float*          Xb  = X  + (size_t)grow0 * K_;
  const unsigned short* P0b = P0 + ((size_t)e * 1024 + nloc0) * K_;
  const unsigned short* P1b = P1 + ((size_t)e * 1024 + nloc0) * K_;

  f32x4 acc[4][4];
#pragma unroll
  for (int i = 0; i < 4; ++i)
#pragma unroll
    for (int j = 0; j < 4; ++j) acc[i][j] = (f32x4){0.f, 0.f, 0.f, 0.f};

  // staging geometry: thread covers rows rA+16s (s<8), cols cA..cA+3
  const int rA = tid >> 4;          // 0..15
  const int cA = (tid & 15) * 4;    // elem col 0..60

  float4  aR[8];
  ushort4 b0R[8], b1R[8];

  auto load_regs = [&](int t) {
    const int kb = t * 64;
#pragma unroll
    for (int s = 0; s < 8; ++s) {
      int r = rA + s * 16;
      aR[s]  = *(const float4*)(Xb + (size_t)r * K_ + kb + cA);
      b0R[s] = *(const ushort4*)(P0b + (size_t)r * K_ + kb + cA);
      b1R[s] = *(const ushort4*)(P1b + (size_t)r * K_ + kb + cA);
    }
  };

  auto write_lds = [&](int t) {
    char* As = lds[t & 1];
    char* Bs = lds[t & 1] + 16384;
#pragma unroll
    for (int s = 0; s < 8; ++s) {
      int r  = rA + s * 16;
      int cb = (cA * 2) ^ ((r & 7) << 4);   // 8B-aligned (XOR flips bits 4-6)
      ushort4 va = {f2bf(aR[s].x), f2bf(aR[s].y), f2bf(aR[s].z), f2bf(aR[s].w)};
      *(ushort4*)(As + r * 128 + cb) = va;
      ushort4 vb = {f2bf(bf2f(b0R[s].x) + bf2f(b1R[s].x)),
                    f2bf(bf2f(b0R[s].y) + bf2f(b1R[s].y)),
                    f2bf(bf2f(b0R[s].z) + bf2f(b1R[s].z)),
                    f2bf(bf2f(b0R[s].w) + bf2f(b1R[s].w))};
      *(ushort4*)(Bs + r * 128 + cb) = vb;
    }
  };

  load_regs(0);
  WAITVM(0);
  write_lds(0);
  BARRIER();

  for (int t = 0; t < NT; ++t) {
    if (t + 1 < NT) load_regs(t + 1);   // issue t+1 global loads early

    char* Ab = lds[t & 1];
    char* Bb = lds[t & 1] + 16384;
    bf16x8 af[4][2], bf[4][2];
#pragma unroll
    for (int mi = 0; mi < 4; ++mi) {
      int r = wm * 64 + mi * 16 + fr;
#pragma unroll
      for (int k = 0; k < 2; ++k)
        af[mi][k] = *(bf16x8*)(Ab + r * 128 + ((k * 64 + fq * 16) ^ ((r & 7) << 4)));
    }
#pragma unroll
    for (int ni = 0; ni < 4; ++ni) {
      int r = wn * 64 + ni * 16 + fr;
#pragma unroll
      for (int k = 0; k < 2; ++k)
        bf[ni][k] = *(bf16x8*)(Bb + r * 128 + ((k * 64 + fq * 16) ^ ((r & 7) << 4)));
    }
    WAITLG(0);
    __builtin_amdgcn_s_setprio(1);
#pragma unroll
    for (int k = 0; k < 2; ++k)
#pragma unroll
      for (int mi = 0; mi < 4; ++mi)
#pragma unroll
        for (int ni = 0; ni < 4; ++ni)
          acc[mi][ni] = __builtin_amdgcn_mfma_f32_16x16x32_bf16(
              af[mi][k], bf[ni][k], acc[mi][ni], 0, 0, 0);
    __builtin_amdgcn_s_setprio(0);

    if (t + 1 < NT) {
      WAITVM(0);           // t+1 loads landed (hidden under MFMA)
      write_lds(t + 1);    // opposite buffer: no WAR with current reads
    }
    BARRIER();             // my reads of buf[t&1] done everywhere; t+1 visible
  }

  // epilogue: D layout col=lane&15 (n), row=(lane>>4)*4+reg (m)  [m89]
#pragma unroll
  for (int ni = 0; ni < 4; ++ni) {
    int ncol = nloc0 + wn * 64 + ni * 16 + fr;
    float bv = (bias + (size_t)e * N_)[ncol];
#pragma unroll
    for (int mi = 0; mi < 4; ++mi) {
      int m = grow0 + wm * 64 + mi * 16 + fq * 4;
#pragma unroll
      for (int j = 0; j < 4; ++j)
        C[(size_t)(m + j) * N_ + ncol] = acc[mi][ni][j] + bv;
    }
  }
}

// ---------------------------------------------------------------------------
// Proven fallback templates (low-ws paths only)
// ---------------------------------------------------------------------------
DEV int swz(int r, int cbyte) {
  return (r * 64 + cbyte) ^ (((r >> 1) & 7) << 4);
}

template <int K_, int N_, bool OUT_BF16, bool HAS_BIAS, int EDIV>
__global__ __launch_bounds__(512, 2)
void gemm8(const unsigned short* __restrict__ A,
           const unsigned short* __restrict__ B,
           const float* __restrict__ bias, void* __restrict__ Cv) {
  __shared__ __align__(128) char lds[2][49152];
  const int t    = threadIdx.x;
  const int lane = t & 63;
  const int wv   = t >> 6;
  const int wm   = wv >> 1;
  const int wn   = wv & 1;
  const int fr   = lane & 15;
  const int fq   = lane >> 4;
  constexpr int NCT = N_ / 128;
  constexpr int NT  = K_ / 64;

  int bid = blockIdx.x;
  const int nwg = gridDim.x;
  bid = (bid & 7) * (nwg >> 3) + (bid >> 3);
  const int rt = bid / NCT;
  const int ct = bid - rt * NCT;

  int e;
  if constexpr (EDIV > 0) {
    e = rt / EDIV;
  } else {
    const int cums[9] = {0, 2, 6, 14, 30, 34, 36, 44, 48};
    e = 0;
#pragma unroll
    for (int i = 1; i < 8; ++i) e += (rt >= cums[i]) ? 1 : 0;
  }

  const int grow0 = rt * 256;
  const int nloc0 = ct * 128;
  const unsigned short* Bg = B + (size_t)e * N_ * K_;

  f32x4 acc[4][4];
#pragma unroll
  for (int i = 0; i < 4; ++i)
#pragma unroll
    for (int j = 0; j < 4; ++j) acc[i][j] = (f32x4){0.f, 0.f, 0.f, 0.f};

  auto stage = [&](int buf, int tk) {
    const int kb = tk * 64;
    char* Abase = lds[buf];
    char* Bbase = lds[buf] + 32768;
#pragma unroll
    for (int s = 0; s < 4; ++s) {
      int o  = s * 8192 + wv * 1024 + lane * 16;
      int r  = o >> 7;
      int cb = (o & 127) ^ ((r & 7) << 4);
      gld_lds16(A + (size_t)(grow0 + r) * K_ + kb + (cb >> 1),
                Abase + s * 8192 + wv * 1024);
    }
#pragma unroll
    for (int s = 0; s < 2; ++s) {
      int o  = s * 8192 + wv * 1024 + lane * 16;
      int r  = o >> 7;
      int cb = (o & 127) ^ ((r & 7) << 4);
      gld_lds16(Bg + (size_t)(nloc0 + r) * K_ + kb + (cb >> 1),
                Bbase + s * 8192 + wv * 1024);
    }
  };

  auto compute = [&](int buf) {
    char* Abase = lds[buf];
    char* Bbase = lds[buf] + 32768;
    bf16x8 af[4][2], bf[4][2];
#pragma unroll
    for (int mi = 0; mi < 4; ++mi) {
      int r = wm * 64 + mi * 16 + fr;
#pragma unroll
      for (int k = 0; k < 2; ++k)
        af[mi][k] = *(bf16x8*)(Abase + r * 128 + ((k * 64 + fq * 16) ^ ((r & 7) << 4)));
    }
#pragma unroll
    for (int ni = 0; ni < 4; ++ni) {
      int r = wn * 64 + ni * 16 + fr;
#pragma unroll
      for (int k = 0; k < 2; ++k)
        bf[ni][k] = *(bf16x8*)(Bbase + r * 128 + ((k * 64 + fq * 16) ^ ((r & 7) << 4)));
    }
    __builtin_amdgcn_s_setprio(1);
#pragma unroll
    for (int k = 0; k < 2; ++k)
#pragma unroll
      for (int mi = 0; mi < 4; ++mi)
#pragma unroll
        for (int ni = 0; ni < 4; ++ni)
          acc[mi][ni] = __builtin_amdgcn_mfma_f32_16x16x32_bf16(
              af[mi][k], bf[ni][k], acc[mi][ni], 0, 0, 0);
    __builtin_amdgcn_s_setprio(0);
  };

  stage(0, 0);
  for (int tk = 0; tk < NT; ++tk) {
    const int cur = tk & 1;
    if (tk + 1 < NT) {
      stage(cur ^ 1, tk + 1);
      WAITVM(6);
    } else {
      WAITVM(0);
    }
    __builtin_amdgcn_s_barrier();
    compute(cur);
    WAITLG(0);
    __builtin_amdgcn_s_barrier();
  }

#pragma unroll
  for (int ni = 0; ni < 4; ++ni) {
    int nloc = nloc0 + wn * 64 + ni * 16 + fr;
    float bv = 0.f;
    if constexpr (HAS_BIAS) bv = (bias + (size_t)e * N_)[nloc];
#pragma unroll
    for (int mi = 0; mi < 4; ++mi) {
      int m = grow0 + wm * 64 + mi * 16 + fq * 4;
#pragma unroll
      for (int j = 0; j < 4; ++j) {
        float val = acc[mi][ni][j] + bv;
        if constexpr (OUT_BF16)
          ((unsigned short*)Cv)[(size_t)(m + j) * N_ + nloc] = f2bf(val);
        else
          ((float*)Cv)[(size_t)(m + j) * N_ + nloc] = val;
      }
    }
  }
}

template <int K_, int N_, int NCT_, bool OUT_BF16, bool HAS_BIAS, int EDIV>
__global__ __launch_bounds__(256)
void gemm_expert(const void* __restrict__ Av, const void* __restrict__ Bv,
                 const float* __restrict__ bias, void* __restrict__ Cv) {
  __shared__ char lds[2][12288];
  const int t    = threadIdx.x;
  const int lane = t & 63;
  const int wv   = t >> 6;
  const int wr   = wv >> 1;
  const int wc   = wv & 1;
  const int fr   = lane & 15;
  const int fq   = lane >> 4;

  int bid = blockIdx.x;
  const int nwg = gridDim.x;
  if ((nwg & 7) == 0) bid = (bid & 7) * (nwg >> 3) + (bid >> 3);
  const int rt = bid / NCT_;
  const int ct = bid - rt * NCT_;

  int e;
  if constexpr (EDIV > 0) {
    e = rt / EDIV;
  } else {
    const int cums[9] = {0, 4, 12, 28, 60, 68, 72, 88, 96};
    e = 0;
#pragma unroll
    for (int i = 1; i < 8; ++i) e += (rt >= cums[i]) ? 1 : 0;
  }

  const int grow0 = rt * 128;
  const int nloc0 = ct * 64;

  f32x4 acc[4][2];
#pragma unroll
  for (int i = 0; i < 4; ++i)
#pragma unroll
    for (int j = 0; j < 2; ++j) acc[i][j] = (f32x4){0.f, 0.f, 0.f, 0.f};

  const float* Af = (const float*)Av;
  const unsigned short* Bb = (const unsigned short*)Bv + (size_t)e * N_ * K_;

  auto stage = [&](int buf, int kb) {
    char* As = lds[buf];
    char* Bs = lds[buf] + 8192;
#pragma unroll
    for (int it = 0; it < 4; ++it) {
      int q = t + it * 256, r = q >> 3, c = (q & 7) * 4;
      float4 f = *(const float4*)(Af + (size_t)(grow0 + r) * K_ + kb + c);
      ushort4 v = {f2bf(f.x), f2bf(f.y), f2bf(f.z), f2bf(f.w)};
      *(ushort4*)(As + swz(r, c * 2)) = v;
    }
    int o = wv * 1024 + lane * 16;
    int p = o ^ (((o >> 7) & 7) << 4);
    gld_lds16(Bb + (size_t)(nloc0 + (p >> 6)) * K_ + kb + ((p & 63) >> 1),
              Bs + wv * 1024);
  };

  auto compute = [&](int buf) {
    char* As = lds[buf];
    char* Bs = lds[buf] + 8192;
    bf16x8 af[4], bfg[2];
#pragma unroll
    for (int mi = 0; mi < 4; ++mi)
      af[mi] = *(bf16x8*)(As + swz(wr * 64 + mi * 16 + fr, fq * 16));
#pragma unroll
    for (int ni = 0; ni < 2; ++ni)
      bfg[ni] = *(bf16x8*)(Bs + swz(wc * 32 + ni * 16 + fr, fq * 16));
#pragma unroll
    for (int mi = 0; mi < 4; ++mi)
#pragma unroll
      for (int ni = 0; ni < 2; ++ni)
        acc[mi][ni] = __builtin_amdgcn_mfma_f32_16x16x32_bf16(
            af[mi], bfg[ni], acc[mi][ni], 0, 0, 0);
  };

  int cur = 0;
  stage(0, 0);
  __syncthreads();
  for (int kb = 32; kb < K_; kb += 32) {
    stage(cur ^ 1, kb);
    compute(cur);
    __syncthreads();
    cur ^= 1;
  }
  compute(cur);

#pragma unroll
  for (int ni = 0; ni < 2; ++ni) {
    int nloc = nloc0 + wc * 32 + ni * 16 + fr;
    float bv = 0.f;
    if constexpr (HAS_BIAS) bv = (bias + (size_t)e * N_)[nloc];
#pragma unroll
    for (int mi = 0; mi < 4; ++mi) {
      int m = grow0 + wr * 64 + mi * 16 + fq * 4;
#pragma unroll
      for (int j = 0; j < 4; ++j) {
        float val = acc[mi][ni][j] + bv;
        if constexpr (OUT_BF16)
          ((unsigned short*)Cv)[(size_t)(m + j) * N_ + nloc] = f2bf(val);
        else
          ((float*)Cv)[(size_t)(m + j) * N_ + nloc] = val;
      }
    }
  }
}

// w1 (E,4096,1024) f32 -> w1t (E,1024,4096) bf16, 64x64 tiles via LDS
__global__ __launch_bounds__(256)
void transpose_w1(const float* __restrict__ w1, unsigned short* __restrict__ w1t) {
  __shared__ unsigned short tl[64 * 68];
  int b = blockIdx.x;
  int jt = b & 15, kt = (b >> 4) & 63, e = b >> 10;
  const float* src = w1 + ((size_t)e * 4096 + kt * 64) * 1024 + jt * 64;
  int t = threadIdx.x;
#pragma unroll
  for (int it = 0; it < 4; ++it) {
    int q = t + it * 256, kr = q >> 4, jc = (q & 15) * 4;
    float4 f = *(const float4*)(src + (size_t)kr * 1024 + jc);
    ushort4 v = {f2bf(f.x), f2bf(f.y), f2bf(f.z), f2bf(f.w)};
    *(ushort4*)&tl[kr * 68 + jc] = v;
  }
  __syncthreads();
  unsigned short* dst = w1t + ((size_t)e * 1024 + jt * 64) * 4096 + kt * 64;
#pragma unroll
  for (int it = 0; it < 4; ++it) {
    int q = t + it * 256, jr = q >> 4, kc = (q & 15) * 4;
    ushort4 v = {tl[(kc + 0) * 68 + jr], tl[(kc + 1) * 68 + jr],
                 tl[(kc + 2) * 68 + jr], tl[(kc + 3) * 68 + jr]};
    *(ushort4*)(dst + (size_t)jr * 4096 + kc) = v;
  }
}

template <bool STORE_BF>
__global__ __launch_bounds__(256)
void conv_w2_bias(const float* __restrict__ w2, const float* __restrict__ b1,
                  const float* __restrict__ b2, unsigned short* __restrict__ w2bf,
                  float* __restrict__ bc) {
  int row = blockIdx.x, e = row >> 10, t = threadIdx.x;
  const float* src = w2 + (size_t)row * 4096;
  const float* b1e = b1 + (size_t)e * 4096;
  float acc = 0.f;
#pragma unroll
  for (int it = 0; it < 4; ++it) {
    int c = (t + it * 256) * 4;
    float4 f = *(const float4*)(src + c);
    float4 g = *(const float4*)(b1e + c);
    acc += f.x * g.x + f.y * g.y + f.z * g.z + f.w * g.w;
    if constexpr (STORE_BF) {
      ushort4 v = {f2bf(f.x), f2bf(f.y), f2bf(f.z), f2bf(f.w)};
      *(ushort4*)(w2bf + (size_t)row * 4096 + c) = v;
    }
  }
#pragma unroll
  for (int o = 32; o > 0; o >>= 1) acc += __shfl_down(acc, o);
  __shared__ float red[4];
  if ((t & 63) == 0) red[t >> 6] = acc;
  __syncthreads();
  if (t == 0) bc[row] = red[0] + red[1] + red[2] + red[3] + b2[row];
}

extern "C" void kernel_launch(void* const* d_in, const int* in_sizes, int n_in,
                              void* d_out, int out_size, void* d_ws, size_t ws_size,
                              hipStream_t stream) {
  const float* x  = (const float*)d_in[0];   // (12288, 1024)
  const float* w1 = (const float*)d_in[1];   // (8, 4096, 1024)
  const float* b1 = (const float*)d_in[2];   // (8, 4096)
  const float* w2 = (const float*)d_in[3];   // (8, 1024, 4096)
  const float* b2 = (const float*)d_in[4];   // (8, 1024)

  char* ws = (char*)d_ws;
  unsigned short* w1t = (unsigned short*)ws;              // 64 MiB
  const size_t NEED_T2 = 151126016, NEED_T3 = 167903232;

  if (ws_size >= NEED_T3) {
    unsigned short* w2bf = (unsigned short*)(ws + 67108864);   // 64 MiB
    unsigned short* p0   = (unsigned short*)(ws + 134217728);  // 16 MiB
    float*          bc   = (float*)(ws + 150994944);           // 32 KiB
    unsigned short* p1   = (unsigned short*)(ws + 151126016);  // 16 MiB

    transpose_w1<<<8192, 256, 0, stream>>>(w1, w1t);
    conv_w2_bias<true><<<8192, 256, 0, stream>>>(w2, b1, b2, w2bf, bc);
    // Wc partials: p0/p1 = split-K halves of w2bf @ w1t^T (M=8192,N=1024,K=4096)
    gemm256p<4096, 2048, 2, 1024, 4, true, false, 4>
        <<<256, 512, 0, stream>>>(w2bf, w1t, nullptr, p0, p1);
    // out = x @ (p0+p1)^T + bc : reduce + x-conversion fused into staging
    gemm128rs<<<768, 256, 0, stream>>>(x, p0, p1, bc, (float*)d_out);
  } else if (ws_size >= NEED_T2) {
    unsigned short* w2bf = (unsigned short*)(ws + 67108864);
    unsigned short* Wc   = (unsigned short*)(ws + 134217728);
    float*          bc   = (float*)(ws + 150994944);

    transpose_w1<<<8192, 256, 0, stream>>>(w1, w1t);
    conv_w2_bias<true><<<8192, 256, 0, stream>>>(w2, b1, b2, w2bf, bc);
    gemm8<4096, 1024, true, false, 4>
        <<<256, 512, 0, stream>>>(w2bf, w1t, nullptr, Wc);
    gemm_expert<1024, 1024, 16, false, true, 0>
        <<<1536, 256, 0, stream>>>(x, Wc, bc, d_out);
  } else {
    // P2 fallback (84 MiB): f32-staged everywhere
    unsigned short* Wc = (unsigned short*)(ws + 67108864);
    float*          bc = (float*)(ws + 83886080);

    transpose_w1<<<8192, 256, 0, stream>>>(w1, w1t);
    conv_w2_bias<false><<<8192, 256, 0, stream>>>(w2, b1, b2, nullptr, bc);
    gemm_expert<4096, 1024, 8, true, false, 8>
        <<<768, 256, 0, stream>>>(w2, w1t, nullptr, Wc);
    gemm_expert<1024, 1024, 16, false, true, 0>
        <<<1536, 256, 0, stream>>>(x, Wc, bc, d_out);
  }
}

// Round 15
// 200.961 us; speedup vs baseline: 1.1488x; 1.1488x over previous
//
#include <hip/hip_runtime.h>
#include <hip/hip_bf16.h>

#define DEV __device__ __forceinline__

typedef __bf16 bf16x8 __attribute__((ext_vector_type(8)));
typedef float  f32x4  __attribute__((ext_vector_type(4)));

// caps = {512,1024,2048,4096,1024,512,2048,1024}
// 128-row-tile cumsum: {0,4,12,28,60,68,72,88,96}
// 256-row-tile cumsum: {0,2,6,14,30,34,36,44,48}

DEV unsigned short f2bf(float f) {
  union { float f; unsigned u; } v; v.f = f;
  unsigned u = v.u;
  return (unsigned short)((u + 0x7FFFu + ((u >> 16) & 1u)) >> 16);  // RNE
}

DEV float bf2f(unsigned short s) {
  union { unsigned u; float f; } v; v.u = (unsigned)s << 16; return v.f;
}

DEV void gld_lds16(const void* g, void* l) {
  __builtin_amdgcn_global_load_lds(
      (const __attribute__((address_space(1))) unsigned int*)g,
      (__attribute__((address_space(3))) unsigned int*)l, 16, 0, 0);
}

#define WAITVM(N) asm volatile("s_waitcnt vmcnt(" #N ")" ::: "memory"); \
                  __builtin_amdgcn_sched_barrier(0)
#define WAITLG(N) asm volatile("s_waitcnt lgkmcnt(" #N ")" ::: "memory"); \
                  __builtin_amdgcn_sched_barrier(0)
#define BARRIER() __builtin_amdgcn_s_barrier(); __builtin_amdgcn_sched_barrier(0)

// ---------------------------------------------------------------------------
// Wc GEMM (round-9 best, 931 TF = 2-phase structure ceiling): 256x256 tile,
// 8 waves 2x4, wave-tile 128x64, BK=64, 128KB LDS, counted vmcnt + register
// fragment pipeline (afX/afY lgkmcnt(4) rotation).
// ---------------------------------------------------------------------------
template <int KT_, int KLEN, int SK, int N_, int NCT, bool OUT_BF16,
          bool HAS_BIAS, int EDIV>
__global__ __launch_bounds__(512, 2)
void gemm256p(const unsigned short* __restrict__ A,
              const unsigned short* __restrict__ B,
              const float* __restrict__ bias,
              void* __restrict__ C0, void* __restrict__ C1) {
  __shared__ __align__(128) char lds[131072];
  constexpr int NT = KLEN / 64;

  const int tid  = threadIdx.x;
  const int lane = tid & 63;
  const int wv   = tid >> 6;
  const int wm   = wv >> 2;      // 0..1  (128 out-rows)
  const int wn   = wv & 3;       // 0..3  (64 out-cols)
  const int fr   = lane & 15;
  const int fq   = lane >> 4;

  int bid = blockIdx.x;
  const int nwg = gridDim.x;
  bid = (bid & 7) * (nwg >> 3) + (bid >> 3);   // XCD swizzle (nwg % 8 == 0)

  int sk = 0;
  if constexpr (SK > 1) {
    const int per = nwg / SK;
    sk = bid / per;
    bid -= sk * per;
  }
  const int kStart = sk * KLEN;
  void* Cv = (SK > 1 && sk == 1) ? C1 : C0;

  const int rt = bid / NCT;
  const int ct = bid - rt * NCT;

  int e;
  if constexpr (EDIV > 0) {
    e = rt / EDIV;
  } else {
    const int cums[9] = {0, 2, 6, 14, 30, 34, 36, 44, 48};
    e = 0;
#pragma unroll
    for (int i = 1; i < 8; ++i) e += (rt >= cums[i]) ? 1 : 0;
  }

  const int grow0 = rt * 256;
  const int nloc0 = ct * 256;
  const unsigned short* Bg = B + (size_t)e * N_ * KT_;

  f32x4 acc[8][4];
#pragma unroll
  for (int i = 0; i < 8; ++i)
#pragma unroll
    for (int j = 0; j < 4; ++j) acc[i][j] = (f32x4){0.f, 0.f, 0.f, 0.f};

  auto stage_half = [&](int t, int h) {
    const int kb = kStart + t * 64;
    char* dst = lds + (h >> 1) * 65536 + (t & 1) * 32768 + (h & 1) * 16384;
    const unsigned short* src = (h < 2) ? A : Bg;
    const int row0 = (h < 2) ? (grow0 + (h & 1) * 128) : (nloc0 + (h & 1) * 128);
#pragma unroll
    for (int s = 0; s < 2; ++s) {
      int o  = s * 8192 + wv * 1024 + lane * 16;
      int r  = o >> 7;
      int cb = (o & 127) ^ ((r & 7) << 4);
      gld_lds16(src + (size_t)(row0 + r) * KT_ + kb + (cb >> 1),
                dst + s * 8192 + wv * 1024);
    }
  };

  stage_half(0, 0); stage_half(0, 1); stage_half(0, 2); stage_half(0, 3);
  if constexpr (NT > 1) { stage_half(1, 2); stage_half(1, 3); }

  const int brow0 = (wn & 1) * 64;

  for (int t = 0; t < NT; ++t) {
    char* Ah = lds + (t & 1) * 32768 + wm * 16384;
    char* Bh = lds + 65536 + (t & 1) * 32768 + ((wn >> 1) * 16384);

    if (t + 1 < NT) { WAITVM(4); } else { WAITVM(0); }
    BARRIER();                       // RAW: tile t visible to ALL waves

    bf16x8 bfr[4][2], afX[2][2], afY[2][2];
#pragma unroll
    for (int ni = 0; ni < 4; ++ni) {
      int r = brow0 + ni * 16 + fr;
#pragma unroll
      for (int k = 0; k < 2; ++k)
        bfr[ni][k] = *(bf16x8*)(Bh + r * 128 + ((k * 64 + fq * 16) ^ ((r & 7) << 4)));
    }
#pragma unroll
    for (int j = 0; j < 2; ++j) {
      int r = j * 16 + fr;
#pragma unroll
      for (int k = 0; k < 2; ++k)
        afX[j][k] = *(bf16x8*)(Ah + r * 128 + ((k * 64 + fq * 16) ^ ((r & 7) << 4)));
    }
#pragma unroll
    for (int j = 0; j < 2; ++j) {
      int r = 32 + j * 16 + fr;
#pragma unroll
      for (int k = 0; k < 2; ++k)
        afY[j][k] = *(bf16x8*)(Ah + r * 128 + ((k * 64 + fq * 16) ^ ((r & 7) << 4)));
    }
    if (t + 1 < NT) stage_half(t + 1, 0);
    WAITLG(4);                       // B + A0 done; A1 outstanding
    BARRIER();                       // WAR: b-slot gen t&1 writable
    __builtin_amdgcn_s_setprio(1);
#pragma unroll
    for (int k = 0; k < 2; ++k)
#pragma unroll
      for (int j = 0; j < 2; ++j)
#pragma unroll
        for (int ni = 0; ni < 4; ++ni)
          acc[j][ni] = __builtin_amdgcn_mfma_f32_16x16x32_bf16(
              afX[j][k], bfr[ni][k], acc[j][ni], 0, 0, 0);
    __builtin_amdgcn_s_setprio(0);
#pragma unroll
    for (int j = 0; j < 2; ++j) {
      int r = 64 + j * 16 + fr;
#pragma unroll
      for (int k = 0; k < 2; ++k)
        afX[j][k] = *(bf16x8*)(Ah + r * 128 + ((k * 64 + fq * 16) ^ ((r & 7) << 4)));
    }
    if (t + 1 < NT) stage_half(t + 1, 1);
    if (t + 2 < NT) stage_half(t + 2, 2);
    WAITLG(4);                       // A1 done; A2 outstanding
    __builtin_amdgcn_s_setprio(1);
#pragma unroll
    for (int k = 0; k < 2; ++k)
#pragma unroll
      for (int j = 0; j < 2; ++j)
#pragma unroll
        for (int ni = 0; ni < 4; ++ni)
          acc[2 + j][ni] = __builtin_amdgcn_mfma_f32_16x16x32_bf16(
              afY[j][k], bfr[ni][k], acc[2 + j][ni], 0, 0, 0);
    __builtin_amdgcn_s_setprio(0);
#pragma unroll
    for (int j = 0; j < 2; ++j) {
      int r = 96 + j * 16 + fr;
#pragma unroll
      for (int k = 0; k < 2; ++k)
        afY[j][k] = *(bf16x8*)(Ah + r * 128 + ((k * 64 + fq * 16) ^ ((r & 7) << 4)));
    }
    if (t + 2 < NT) stage_half(t + 2, 3);
    WAITLG(4);                       // A2 done; A3 outstanding
    __builtin_amdgcn_s_setprio(1);
#pragma unroll
    for (int k = 0; k < 2; ++k)
#pragma unroll
      for (int j = 0; j < 2; ++j)
#pragma unroll
        for (int ni = 0; ni < 4; ++ni)
          acc[4 + j][ni] = __builtin_amdgcn_mfma_f32_16x16x32_bf16(
              afX[j][k], bfr[ni][k], acc[4 + j][ni], 0, 0, 0);
    __builtin_amdgcn_s_setprio(0);
    WAITLG(0);                       // A3 done
    __builtin_amdgcn_s_setprio(1);
#pragma unroll
    for (int k = 0; k < 2; ++k)
#pragma unroll
      for (int j = 0; j < 2; ++j)
#pragma unroll
        for (int ni = 0; ni < 4; ++ni)
          acc[6 + j][ni] = __builtin_amdgcn_mfma_f32_16x16x32_bf16(
              afY[j][k], bfr[ni][k], acc[6 + j][ni], 0, 0, 0);
    __builtin_amdgcn_s_setprio(0);
  }

  // epilogue: D layout col=lane&15 (n), row=(lane>>4)*4+reg (m)  [m89]
#pragma unroll
  for (int ni = 0; ni < 4; ++ni) {
    int ncol = nloc0 + wn * 64 + ni * 16 + fr;
    float bv = 0.f;
    if constexpr (HAS_BIAS) bv = (bias + (size_t)e * N_)[ncol];
#pragma unroll
    for (int mi = 0; mi < 8; ++mi) {
      int m = grow0 + wm * 128 + mi * 16 + fq * 4;
#pragma unroll
      for (int j = 0; j < 4; ++j) {
        float val = acc[mi][ni][j] + bv;
        if constexpr (OUT_BF16)
          ((unsigned short*)Cv)[(size_t)(m + j) * N_ + ncol] = f2bf(val);
        else
          ((float*)Cv)[(size_t)(m + j) * N_ + ncol] = val;
      }
    }
  }
}

// ---------------------------------------------------------------------------
// Final GEMM: 128x128 tile, 4 waves (2x2), wave-tile 64x64, BK=64,
// LDS 64KB dbuf -> 2 resident blocks/CU. Grid 96x8 = 768 blocks.
// Counted vmcnt(8); gld_lds staging with pre-swizzled source.
// ---------------------------------------------------------------------------
template <int K_, int N_, int NCT, bool OUT_BF16, bool HAS_BIAS, int EDIV>
__global__ __launch_bounds__(256, 2)
void gemm128(const unsigned short* __restrict__ A,
             const unsigned short* __restrict__ B,
             const float* __restrict__ bias, void* __restrict__ Cv) {
  __shared__ __align__(128) char lds[2][32768];   // A 16KB + B 16KB per buf
  constexpr int NT = K_ / 64;

  const int tid  = threadIdx.x;
  const int lane = tid & 63;
  const int wv   = tid >> 6;     // 0..3
  const int wm   = wv >> 1;      // 0..1 (64 out-rows)
  const int wn   = wv & 1;       // 0..1 (64 out-cols)
  const int fr   = lane & 15;
  const int fq   = lane >> 4;

  int bid = blockIdx.x;
  const int nwg = gridDim.x;
  bid = (bid & 7) * (nwg >> 3) + (bid >> 3);   // XCD swizzle (nwg % 8 == 0)

  const int rt = bid / NCT;
  const int ct = bid - rt * NCT;

  int e;
  if constexpr (EDIV > 0) {
    e = rt / EDIV;
  } else {
    const int cums[9] = {0, 4, 12, 28, 60, 68, 72, 88, 96};
    e = 0;
#pragma unroll
    for (int i = 1; i < 8; ++i) e += (rt >= cums[i]) ? 1 : 0;
  }

  const int grow0 = rt * 128;
  const int nloc0 = ct * 128;
  const unsigned short* Bg = B + (size_t)e * N_ * K_;

  f32x4 acc[4][4];
#pragma unroll
  for (int i = 0; i < 4; ++i)
#pragma unroll
    for (int j = 0; j < 4; ++j) acc[i][j] = (f32x4){0.f, 0.f, 0.f, 0.f};

  auto stage = [&](int buf, int tk) {
    const int kb = tk * 64;
#pragma unroll
    for (int s = 0; s < 4; ++s) {
      int o  = s * 4096 + wv * 1024 + lane * 16;
      int r  = o >> 7;
      int cb = (o & 127) ^ ((r & 7) << 4);
      gld_lds16(A + (size_t)(grow0 + r) * K_ + kb + (cb >> 1),
                lds[buf] + s * 4096 + wv * 1024);
    }
#pragma unroll
    for (int s = 0; s < 4; ++s) {
      int o  = s * 4096 + wv * 1024 + lane * 16;
      int r  = o >> 7;
      int cb = (o & 127) ^ ((r & 7) << 4);
      gld_lds16(Bg + (size_t)(nloc0 + r) * K_ + kb + (cb >> 1),
                lds[buf] + 16384 + s * 4096 + wv * 1024);
    }
  };

  stage(0, 0);
  for (int t = 0; t < NT; ++t) {
    const int cur = t & 1;
    if (t + 1 < NT) {
      stage(cur ^ 1, t + 1);
      WAITVM(8);               // retire exactly tile t; t+1 stays in flight
    } else {
      WAITVM(0);
    }
    BARRIER();                 // tile t visible to all 4 waves

    char* Ab = lds[cur];
    char* Bb = lds[cur] + 16384;
    bf16x8 af[4][2], bf[4][2];
#pragma unroll
    for (int mi = 0; mi < 4; ++mi) {
      int r = wm * 64 + mi * 16 + fr;
#pragma unroll
      for (int k = 0; k < 2; ++k)
        af[mi][k] = *(bf16x8*)(Ab + r * 128 + ((k * 64 + fq * 16) ^ ((r & 7) << 4)));
    }
#pragma unroll
    for (int ni = 0; ni < 4; ++ni) {
      int r = wn * 64 + ni * 16 + fr;
#pragma unroll
      for (int k = 0; k < 2; ++k)
        bf[ni][k] = *(bf16x8*)(Bb + r * 128 + ((k * 64 + fq * 16) ^ ((r & 7) << 4)));
    }
    WAITLG(0);
    __builtin_amdgcn_s_setprio(1);
#pragma unroll
    for (int k = 0; k < 2; ++k)
#pragma unroll
      for (int mi = 0; mi < 4; ++mi)
#pragma unroll
        for (int ni = 0; ni < 4; ++ni)
          acc[mi][ni] = __builtin_amdgcn_mfma_f32_16x16x32_bf16(
              af[mi][k], bf[ni][k], acc[mi][ni], 0, 0, 0);
    __builtin_amdgcn_s_setprio(0);
    BARRIER();                 // all waves' reads done -> buf reusable
  }

  // epilogue: D layout col=lane&15 (n), row=(lane>>4)*4+reg (m)  [m89]
#pragma unroll
  for (int ni = 0; ni < 4; ++ni) {
    int ncol = nloc0 + wn * 64 + ni * 16 + fr;
    float bv = 0.f;
    if constexpr (HAS_BIAS) bv = (bias + (size_t)e * N_)[ncol];
#pragma unroll
    for (int mi = 0; mi < 4; ++mi) {
      int m = grow0 + wm * 64 + mi * 16 + fq * 4;
#pragma unroll
      for (int j = 0; j < 4; ++j) {
        float val = acc[mi][ni][j] + bv;
        if constexpr (OUT_BF16)
          ((unsigned short*)Cv)[(size_t)(m + j) * N_ + ncol] = f2bf(val);
        else
          ((float*)Cv)[(size_t)(m + j) * N_ + ncol] = val;
      }
    }
  }
}

// out[i] = bf16( f32(p0[i]) + f32(p1[i]) )  -- split-K reduce
__global__ __launch_bounds__(256)
void reduce_bf16(const unsigned short* __restrict__ p0,
                 const unsigned short* __restrict__ p1,
                 unsigned short* __restrict__ out, int n8) {
  for (int i = blockIdx.x * 256 + threadIdx.x; i < n8; i += gridDim.x * 256) {
    ushort4 a0 = ((const ushort4*)p0)[2 * i];
    ushort4 a1 = ((const ushort4*)p0)[2 * i + 1];
    ushort4 b0 = ((const ushort4*)p1)[2 * i];
    ushort4 b1 = ((const ushort4*)p1)[2 * i + 1];
    ushort4 r0 = {f2bf(bf2f(a0.x) + bf2f(b0.x)), f2bf(bf2f(a0.y) + bf2f(b0.y)),
                  f2bf(bf2f(a0.z) + bf2f(b0.z)), f2bf(bf2f(a0.w) + bf2f(b0.w))};
    ushort4 r1 = {f2bf(bf2f(a1.x) + bf2f(b1.x)), f2bf(bf2f(a1.y) + bf2f(b1.y)),
                  f2bf(bf2f(a1.z) + bf2f(b1.z)), f2bf(bf2f(a1.w) + bf2f(b1.w))};
    ((ushort4*)out)[2 * i]     = r0;
    ((ushort4*)out)[2 * i + 1] = r1;
  }
}

// ---------------------------------------------------------------------------
// Proven fallback templates (low-ws paths only)
// ---------------------------------------------------------------------------
DEV int swz(int r, int cbyte) {
  return (r * 64 + cbyte) ^ (((r >> 1) & 7) << 4);
}

template <int K_, int N_, bool OUT_BF16, bool HAS_BIAS, int EDIV>
__global__ __launch_bounds__(512, 2)
void gemm8(const unsigned short* __restrict__ A,
           const unsigned short* __restrict__ B,
           const float* __restrict__ bias, void* __restrict__ Cv) {
  __shared__ __align__(128) char lds[2][49152];
  const int t    = threadIdx.x;
  const int lane = t & 63;
  const int wv   = t >> 6;
  const int wm   = wv >> 1;
  const int wn   = wv & 1;
  const int fr   = lane & 15;
  const int fq   = lane >> 4;
  constexpr int NCT = N_ / 128;
  constexpr int NT  = K_ / 64;

  int bid = blockIdx.x;
  const int nwg = gridDim.x;
  bid = (bid & 7) * (nwg >> 3) + (bid >> 3);
  const int rt = bid / NCT;
  const int ct = bid - rt * NCT;

  int e;
  if constexpr (EDIV > 0) {
    e = rt / EDIV;
  } else {
    const int cums[9] = {0, 2, 6, 14, 30, 34, 36, 44, 48};
    e = 0;
#pragma unroll
    for (int i = 1; i < 8; ++i) e += (rt >= cums[i]) ? 1 : 0;
  }

  const int grow0 = rt * 256;
  const int nloc0 = ct * 128;
  const unsigned short* Bg = B + (size_t)e * N_ * K_;

  f32x4 acc[4][4];
#pragma unroll
  for (int i = 0; i < 4; ++i)
#pragma unroll
    for (int j = 0; j < 4; ++j) acc[i][j] = (f32x4){0.f, 0.f, 0.f, 0.f};

  auto stage = [&](int buf, int tk) {
    const int kb = tk * 64;
    char* Abase = lds[buf];
    char* Bbase = lds[buf] + 32768;
#pragma unroll
    for (int s = 0; s < 4; ++s) {
      int o  = s * 8192 + wv * 1024 + lane * 16;
      int r  = o >> 7;
      int cb = (o & 127) ^ ((r & 7) << 4);
      gld_lds16(A + (size_t)(grow0 + r) * K_ + kb + (cb >> 1),
                Abase + s * 8192 + wv * 1024);
    }
#pragma unroll
    for (int s = 0; s < 2; ++s) {
      int o  = s * 8192 + wv * 1024 + lane * 16;
      int r  = o >> 7;
      int cb = (o & 127) ^ ((r & 7) << 4);
      gld_lds16(Bg + (size_t)(nloc0 + r) * K_ + kb + (cb >> 1),
                Bbase + s * 8192 + wv * 1024);
    }
  };

  auto compute = [&](int buf) {
    char* Abase = lds[buf];
    char* Bbase = lds[buf] + 32768;
    bf16x8 af[4][2], bf[4][2];
#pragma unroll
    for (int mi = 0; mi < 4; ++mi) {
      int r = wm * 64 + mi * 16 + fr;
#pragma unroll
      for (int k = 0; k < 2; ++k)
        af[mi][k] = *(bf16x8*)(Abase + r * 128 + ((k * 64 + fq * 16) ^ ((r & 7) << 4)));
    }
#pragma unroll
    for (int ni = 0; ni < 4; ++ni) {
      int r = wn * 64 + ni * 16 + fr;
#pragma unroll
      for (int k = 0; k < 2; ++k)
        bf[ni][k] = *(bf16x8*)(Bbase + r * 128 + ((k * 64 + fq * 16) ^ ((r & 7) << 4)));
    }
    __builtin_amdgcn_s_setprio(1);
#pragma unroll
    for (int k = 0; k < 2; ++k)
#pragma unroll
      for (int mi = 0; mi < 4; ++mi)
#pragma unroll
        for (int ni = 0; ni < 4; ++ni)
          acc[mi][ni] = __builtin_amdgcn_mfma_f32_16x16x32_bf16(
              af[mi][k], bf[ni][k], acc[mi][ni], 0, 0, 0);
    __builtin_amdgcn_s_setprio(0);
  };

  stage(0, 0);
  for (int tk = 0; tk < NT; ++tk) {
    const int cur = tk & 1;
    if (tk + 1 < NT) {
      stage(cur ^ 1, tk + 1);
      WAITVM(6);
    } else {
      WAITVM(0);
    }
    __builtin_amdgcn_s_barrier();
    compute(cur);
    WAITLG(0);
    __builtin_amdgcn_s_barrier();
  }

#pragma unroll
  for (int ni = 0; ni < 4; ++ni) {
    int nloc = nloc0 + wn * 64 + ni * 16 + fr;
    float bv = 0.f;
    if constexpr (HAS_BIAS) bv = (bias + (size_t)e * N_)[nloc];
#pragma unroll
    for (int mi = 0; mi < 4; ++mi) {
      int m = grow0 + wm * 64 + mi * 16 + fq * 4;
#pragma unroll
      for (int j = 0; j < 4; ++j) {
        float val = acc[mi][ni][j] + bv;
        if constexpr (OUT_BF16)
          ((unsigned short*)Cv)[(size_t)(m + j) * N_ + nloc] = f2bf(val);
        else
          ((float*)Cv)[(size_t)(m + j) * N_ + nloc] = val;
      }
    }
  }
}

template <int K_, int N_, int NCT_, bool OUT_BF16, bool HAS_BIAS, int EDIV>
__global__ __launch_bounds__(256)
void gemm_expert(const void* __restrict__ Av, const void* __restrict__ Bv,
                 const float* __restrict__ bias, void* __restrict__ Cv) {
  __shared__ char lds[2][12288];
  const int t    = threadIdx.x;
  const int lane = t & 63;
  const int wv   = t >> 6;
  const int wr   = wv >> 1;
  const int wc   = wv & 1;
  const int fr   = lane & 15;
  const int fq   = lane >> 4;

  int bid = blockIdx.x;
  const int nwg = gridDim.x;
  if ((nwg & 7) == 0) bid = (bid & 7) * (nwg >> 3) + (bid >> 3);
  const int rt = bid / NCT_;
  const int ct = bid - rt * NCT_;

  int e;
  if constexpr (EDIV > 0) {
    e = rt / EDIV;
  } else {
    const int cums[9] = {0, 4, 12, 28, 60, 68, 72, 88, 96};
    e = 0;
#pragma unroll
    for (int i = 1; i < 8; ++i) e += (rt >= cums[i]) ? 1 : 0;
  }

  const int grow0 = rt * 128;
  const int nloc0 = ct * 64;

  f32x4 acc[4][2];
#pragma unroll
  for (int i = 0; i < 4; ++i)
#pragma unroll
    for (int j = 0; j < 2; ++j) acc[i][j] = (f32x4){0.f, 0.f, 0.f, 0.f};

  const float* Af = (const float*)Av;
  const unsigned short* Bb = (const unsigned short*)Bv + (size_t)e * N_ * K_;

  auto stage = [&](int buf, int kb) {
    char* As = lds[buf];
    char* Bs = lds[buf] + 8192;
#pragma unroll
    for (int it = 0; it < 4; ++it) {
      int q = t + it * 256, r = q >> 3, c = (q & 7) * 4;
      float4 f = *(const float4*)(Af + (size_t)(grow0 + r) * K_ + kb + c);
      ushort4 v = {f2bf(f.x), f2bf(f.y), f2bf(f.z), f2bf(f.w)};
      *(ushort4*)(As + swz(r, c * 2)) = v;
    }
    int o = wv * 1024 + lane * 16;
    int p = o ^ (((o >> 7) & 7) << 4);
    gld_lds16(Bb + (size_t)(nloc0 + (p >> 6)) * K_ + kb + ((p & 63) >> 1),
              Bs + wv * 1024);
  };

  auto compute = [&](int buf) {
    char* As = lds[buf];
    char* Bs = lds[buf] + 8192;
    bf16x8 af[4], bfg[2];
#pragma unroll
    for (int mi = 0; mi < 4; ++mi)
      af[mi] = *(bf16x8*)(As + swz(wr * 64 + mi * 16 + fr, fq * 16));
#pragma unroll
    for (int ni = 0; ni < 2; ++ni)
      bfg[ni] = *(bf16x8*)(Bs + swz(wc * 32 + ni * 16 + fr, fq * 16));
#pragma unroll
    for (int mi = 0; mi < 4; ++mi)
#pragma unroll
      for (int ni = 0; ni < 2; ++ni)
        acc[mi][ni] = __builtin_amdgcn_mfma_f32_16x16x32_bf16(
            af[mi], bfg[ni], acc[mi][ni], 0, 0, 0);
  };

  int cur = 0;
  stage(0, 0);
  __syncthreads();
  for (int kb = 32; kb < K_; kb += 32) {
    stage(cur ^ 1, kb);
    compute(cur);
    __syncthreads();
    cur ^= 1;
  }
  compute(cur);

#pragma unroll
  for (int ni = 0; ni < 2; ++ni) {
    int nloc = nloc0 + wc * 32 + ni * 16 + fr;
    float bv = 0.f;
    if constexpr (HAS_BIAS) bv = (bias + (size_t)e * N_)[nloc];
#pragma unroll
    for (int mi = 0; mi < 4; ++mi) {
      int m = grow0 + wr * 64 + mi * 16 + fq * 4;
#pragma unroll
      for (int j = 0; j < 4; ++j) {
        float val = acc[mi][ni][j] + bv;
        if constexpr (OUT_BF16)
          ((unsigned short*)Cv)[(size_t)(m + j) * N_ + nloc] = f2bf(val);
        else
          ((float*)Cv)[(size_t)(m + j) * N_ + nloc] = val;
      }
    }
  }
}

// w1 (E,4096,1024) f32 -> w1t (E,1024,4096) bf16, 64x64 tiles via LDS
__global__ __launch_bounds__(256)
void transpose_w1(const float* __restrict__ w1, unsigned short* __restrict__ w1t) {
  __shared__ unsigned short tl[64 * 68];
  int b = blockIdx.x;
  int jt = b & 15, kt = (b >> 4) & 63, e = b >> 10;
  const float* src = w1 + ((size_t)e * 4096 + kt * 64) * 1024 + jt * 64;
  int t = threadIdx.x;
#pragma unroll
  for (int it = 0; it < 4; ++it) {
    int q = t + it * 256, kr = q >> 4, jc = (q & 15) * 4;
    float4 f = *(const float4*)(src + (size_t)kr * 1024 + jc);
    ushort4 v = {f2bf(f.x), f2bf(f.y), f2bf(f.z), f2bf(f.w)};
    *(ushort4*)&tl[kr * 68 + jc] = v;
  }
  __syncthreads();
  unsigned short* dst = w1t + ((size_t)e * 1024 + jt * 64) * 4096 + kt * 64;
#pragma unroll
  for (int it = 0; it < 4; ++it) {
    int q = t + it * 256, jr = q >> 4, kc = (q & 15) * 4;
    ushort4 v = {tl[(kc + 0) * 68 + jr], tl[(kc + 1) * 68 + jr],
                 tl[(kc + 2) * 68 + jr], tl[(kc + 3) * 68 + jr]};
    *(ushort4*)(dst + (size_t)jr * 4096 + kc) = v;
  }
}

template <bool STORE_BF>
__global__ __launch_bounds__(256)
void conv_w2_bias(const float* __restrict__ w2, const float* __restrict__ b1,
                  const float* __restrict__ b2, unsigned short* __restrict__ w2bf,
                  float* __restrict__ bc) {
  int row = blockIdx.x, e = row >> 10, t = threadIdx.x;
  const float* src = w2 + (size_t)row * 4096;
  const float* b1e = b1 + (size_t)e * 4096;
  float acc = 0.f;
#pragma unroll
  for (int it = 0; it < 4; ++it) {
    int c = (t + it * 256) * 4;
    float4 f = *(const float4*)(src + c);
    float4 g = *(const float4*)(b1e + c);
    acc += f.x * g.x + f.y * g.y + f.z * g.z + f.w * g.w;
    if constexpr (STORE_BF) {
      ushort4 v = {f2bf(f.x), f2bf(f.y), f2bf(f.z), f2bf(f.w)};
      *(ushort4*)(w2bf + (size_t)row * 4096 + c) = v;
    }
  }
#pragma unroll
  for (int o = 32; o > 0; o >>= 1) acc += __shfl_down(acc, o);
  __shared__ float red[4];
  if ((t & 63) == 0) red[t >> 6] = acc;
  __syncthreads();
  if (t == 0) bc[row] = red[0] + red[1] + red[2] + red[3] + b2[row];
}

__global__ __launch_bounds__(256)
void conv_f32_bf16(const float* __restrict__ in, unsigned short* __restrict__ out,
                   int n4) {
  for (int i = blockIdx.x * 256 + threadIdx.x; i < n4; i += gridDim.x * 256) {
    float4 f = *(const float4*)(in + (size_t)i * 4);
    ushort4 v = {f2bf(f.x), f2bf(f.y), f2bf(f.z), f2bf(f.w)};
    *(ushort4*)(out + (size_t)i * 4) = v;
  }
}

extern "C" void kernel_launch(void* const* d_in, const int* in_sizes, int n_in,
                              void* d_out, int out_size, void* d_ws, size_t ws_size,
                              hipStream_t stream) {
  const float* x  = (const float*)d_in[0];   // (12288, 1024)
  const float* w1 = (const float*)d_in[1];   // (8, 4096, 1024)
  const float* b1 = (const float*)d_in[2];   // (8, 4096)
  const float* w2 = (const float*)d_in[3];   // (8, 1024, 4096)
  const float* b2 = (const float*)d_in[4];   // (8, 1024)

  char* ws = (char*)d_ws;
  unsigned short* w1t = (unsigned short*)ws;              // 64 MiB
  const size_t NEED_T2 = 151126016, NEED_T3 = 176291840;

  if (ws_size >= NEED_T3) {
    unsigned short* w2bf = (unsigned short*)(ws + 67108864);   // 64 MiB
    unsigned short* Wc   = (unsigned short*)(ws + 134217728);  // 16 MiB (= SK p0)
    float*          bc   = (float*)(ws + 150994944);           // 32 KiB
    unsigned short* xbf  = (unsigned short*)(ws + 151126016);  // 25 MiB
    unsigned short* p1   = xbf;                                // 16 MiB, dead after reduce

    transpose_w1<<<8192, 256, 0, stream>>>(w1, w1t);
    conv_w2_bias<true><<<8192, 256, 0, stream>>>(w2, b1, b2, w2bf, bc);
    // Wc[e] = w2bf[e] @ w1t[e]^T : M=8192, N=1024, K=4096, split-K=2
    gemm256p<4096, 2048, 2, 1024, 4, true, false, 4>
        <<<256, 512, 0, stream>>>(w2bf, w1t, nullptr, Wc, p1);
    reduce_bf16<<<2048, 256, 0, stream>>>(Wc, p1, Wc, 8 * 1024 * 1024 / 8);
    conv_f32_bf16<<<2048, 256, 0, stream>>>(x, xbf, 12288 * 1024 / 4);
    // out = xbf @ Wc^T + bc : M=12288, N=1024, K=1024 -- 128x128 tile,
    // grid 768, 2 blocks/CU
    gemm128<1024, 1024, 8, false, true, 0>
        <<<768, 256, 0, stream>>>(xbf, Wc, bc, (float*)d_out);
  } else if (ws_size >= NEED_T2) {
    unsigned short* w2bf = (unsigned short*)(ws + 67108864);
    unsigned short* Wc   = (unsigned short*)(ws + 134217728);
    float*          bc   = (float*)(ws + 150994944);

    transpose_w1<<<8192, 256, 0, stream>>>(w1, w1t);
    conv_w2_bias<true><<<8192, 256, 0, stream>>>(w2, b1, b2, w2bf, bc);
    gemm8<4096, 1024, true, false, 4>
        <<<256, 512, 0, stream>>>(w2bf, w1t, nullptr, Wc);
    gemm_expert<1024, 1024, 16, false, true, 0>
        <<<1536, 256, 0, stream>>>(x, Wc, bc, d_out);
  } else {
    // P2 fallback (84 MiB): f32-staged everywhere
    unsigned short* Wc = (unsigned short*)(ws + 67108864);
    float*          bc = (float*)(ws + 83886080);

    transpose_w1<<<8192, 256, 0, stream>>>(w1, w1t);
    conv_w2_bias<false><<<8192, 256, 0, stream>>>(w2, b1, b2, nullptr, bc);
    gemm_expert<4096, 1024, 8, true, false, 8>
        <<<768, 256, 0, stream>>>(w2, w1t, nullptr, Wc);
    gemm_expert<1024, 1024, 16, false, true, 0>
        <<<1536, 256, 0, stream>>>(x, Wc, bc, d_out);
  }
}